// Round 12
// baseline (112.488 us; speedup 1.0000x reference)
//
#include <hip/hip_runtime.h>

// Chamfer distance, pred/target: (4, 8192, 3) fp32.
// Round-10 pk-fp32 inner loop, now ATOMIC-FREE at global scope:
// each block writes fwd partial mins to [b][chunk][i] and bwd partial
// mins to [b][tile][j] (distinct slots -> no init, no memset dispatch,
// no global RMW). reduce1 folds min-over-chunk / min-over-tile + sum.

typedef float f32x2 __attribute__((ext_vector_type(2)));

#define NPTS   8192
#define BATCH  4
#define RPT    8                  // register-resident rows per thread
#define BLOCK  256
#define PTILE  (RPT * BLOCK)      // 2048 rows per block
#define NTILES (NPTS / PTILE)     // 4
#define CHUNK  128                // streamed cols per block
#define NPAIR  (CHUNK / 2)        // 64 column pairs
#define NCHUNK (NPTS / CHUNK)     // 64  -> grid 4*64*4 = 1024 blocks (4/CU)
#define FWDP_N (BATCH * NCHUNK * NPTS)   // 2M floats = 8 MB
#define BWDP_N (BATCH * NTILES * NPTS)   // 128K floats = 512 KB

__global__ __launch_bounds__(BLOCK, 4) void chamfer_pairs(
    const float* __restrict__ pred, const float* __restrict__ target,
    float* __restrict__ fwd_part, float* __restrict__ bwd_part)
{
    __shared__ f32x2 qx2[NPAIR], qy2[NPAIR], qz2[NPAIR], qw2[NPAIR];
    __shared__ int   cmin_s[CHUNK];   // per-block column mins (int bits)

    const int b    = blockIdx.z;
    const int tile = blockIdx.x;
    const int chnk = blockIdx.y;
    const float* __restrict__ P = pred   + b * NPTS * 3;
    const float* __restrict__ Q = target + b * NPTS * 3;

    const int tid = threadIdx.x;
    const int i0  = tile * PTILE + tid;
    const int j0  = chnk * CHUNK;

    if (tid < CHUNK) {
        const float* qp = Q + 3 * (j0 + tid);
        const float qx = qp[0], qy = qp[1], qz = qp[2];
        ((float*)qx2)[tid] = qx;
        ((float*)qy2)[tid] = qy;
        ((float*)qz2)[tid] = qz;
        ((float*)qw2)[tid] = fmaf(qx, qx, fmaf(qy, qy, qz * qz));
        cmin_s[tid] = 0x7F7F7F7F;   // 3.39e38f
    }
    __syncthreads();

    f32x2 pxn2[RPT], pyn2[RPT], pzn2[RPT], p22[RPT];
    float m[RPT];
#pragma unroll
    for (int r = 0; r < RPT; ++r) {
        const float* pp = P + 3 * (i0 + r * BLOCK);
        const float x = pp[0], y = pp[1], z = pp[2];
        const float nx = -2.0f * x, ny = -2.0f * y, nz = -2.0f * z;
        const float p2 = fmaf(x, x, fmaf(y, y, z * z));
        pxn2[r] = (f32x2){nx, nx};
        pyn2[r] = (f32x2){ny, ny};
        pzn2[r] = (f32x2){nz, nz};
        p22[r]  = (f32x2){p2, p2};
        m[r]    = 3.0e38f;
    }

    // per-lane staggered pair index, decorrelated across the 4 waves
    const int soff = (tid & 63) + ((tid >> 6) << 4);

#pragma unroll 2
    for (int jj = 0; jj < NPAIR; ++jj) {
        const int jp = (soff + jj) & (NPAIR - 1);
        const f32x2 qx = qx2[jp];      // ds_read_b64, packed {q[2jp],q[2jp+1]}
        const f32x2 qy = qy2[jp];
        const f32x2 qz = qz2[jp];
        const f32x2 qw = qw2[jp];

        f32x2 d[RPT];
#pragma unroll
        for (int r = 0; r < RPT; ++r) {
            f32x2 t = __builtin_elementwise_fma(pxn2[r], qx, qw);  // |q|^2 - 2p.q
            t = __builtin_elementwise_fma(pyn2[r], qy, t);
            t = __builtin_elementwise_fma(pzn2[r], qz, t);
            m[r] = fminf(fminf(m[r], t.x), t.y);   // v_min3, |p|^2 deferred
            d[r] = t + p22[r];                     // v_pk_add: full d^2 pair
        }
        // col-min trees per half, min3-friendly nesting
        const float cl = fminf(
            fminf(fminf(fminf(d[0].x, d[1].x), d[2].x),
                  fminf(fminf(d[3].x, d[4].x), d[5].x)),
            fminf(d[6].x, d[7].x));
        const float ch = fminf(
            fminf(fminf(fminf(d[0].y, d[1].y), d[2].y),
                  fminf(fminf(d[3].y, d[4].y), d[5].y)),
            fminf(d[6].y, d[7].y));
        atomicMin(&cmin_s[2 * jp],     __float_as_int(cl));
        atomicMin(&cmin_s[2 * jp + 1], __float_as_int(ch));
    }

    // fwd partial mins: distinct slot per (b, chunk, i) -> plain stores
    float* __restrict__ fp = fwd_part + ((size_t)(b * NCHUNK + chnk)) * NPTS;
#pragma unroll
    for (int r = 0; r < RPT; ++r)
        fp[i0 + r * BLOCK] = fmaxf(m[r] + p22[r].x, 0.0f);  // clamp here

    __syncthreads();
    // bwd partial mins: distinct slot per (b, tile, j)
    if (tid < CHUNK)
        bwd_part[((size_t)(b * NTILES + tile)) * NPTS + j0 + tid] =
            fmaxf(__int_as_float(cmin_s[tid]), 0.0f);
}

__global__ __launch_bounds__(256) void chamfer_reduce1(
    const float* __restrict__ fwd_part, const float* __restrict__ bwd_part,
    float* __restrict__ partials)
{
    __shared__ float part[4];
    float s = 0.0f;

    // each block owns 512 consecutive (b,i) indices; 8192/512=16 per batch,
    // so a block never straddles a batch boundary
#pragma unroll
    for (int t = 0; t < 2; ++t) {
        const int gi = blockIdx.x * 512 + t * 256 + threadIdx.x;
        const int b  = gi >> 13;
        const int i  = gi & (NPTS - 1);

        float mf = 3.0e38f;
        const float* fp = fwd_part + ((size_t)b * NCHUNK) * NPTS + i;
#pragma unroll 8
        for (int c = 0; c < NCHUNK; ++c)
            mf = fminf(mf, fp[(size_t)c * NPTS]);
        s += mf;

        float mb = 3.0e38f;
        const float* bp = bwd_part + ((size_t)b * NTILES) * NPTS + i;
#pragma unroll
        for (int c = 0; c < NTILES; ++c)
            mb = fminf(mb, bp[(size_t)c * NPTS]);
        s += mb;
    }

    for (int off = 32; off > 0; off >>= 1)
        s += __shfl_down(s, off, 64);
    if ((threadIdx.x & 63) == 0)
        part[threadIdx.x >> 6] = s;
    __syncthreads();

    if (threadIdx.x == 0)
        partials[blockIdx.x] = part[0] + part[1] + part[2] + part[3];
}

__global__ __launch_bounds__(64) void chamfer_reduce2(
    const float* __restrict__ partials, float* __restrict__ out)
{
    float t = partials[threadIdx.x];
    for (int off = 32; off > 0; off >>= 1)
        t += __shfl_down(t, off, 64);
    if (threadIdx.x == 0)
        out[0] = t * (1.0f / (float)(BATCH * NPTS));  // /32768
}

extern "C" void kernel_launch(void* const* d_in, const int* in_sizes, int n_in,
                              void* d_out, int out_size, void* d_ws, size_t ws_size,
                              hipStream_t stream)
{
    const float* pred   = (const float*)d_in[0];
    const float* target = (const float*)d_in[1];
    float* out = (float*)d_out;
    float* fwd_part = (float*)d_ws;               // [BATCH][NCHUNK][NPTS] 8 MB
    float* bwd_part = fwd_part + FWDP_N;          // [BATCH][NTILES][NPTS] 512 KB
    float* partials = bwd_part + BWDP_N;          // [64]

    dim3 grid(NTILES, NCHUNK, BATCH);
    chamfer_pairs<<<grid, BLOCK, 0, stream>>>(pred, target, fwd_part, bwd_part);
    chamfer_reduce1<<<64, 256, 0, stream>>>(fwd_part, bwd_part, partials);
    chamfer_reduce2<<<1, 64, 0, stream>>>(partials, out);
}

// Round 13
// 90.059 us; speedup vs baseline: 1.2491x; 1.2491x over previous
//
#include <hip/hip_runtime.h>

// Chamfer distance, pred/target: (4, 8192, 3) fp32.
// Round-10 structure (measured best, 90.2 us): memset + pk-fp32 inner loop
// + global int atomicMin into 256 KB mins. Deltas vs r10:
//   (1) single fused reduce kernel (1 block x 1024 thr, int4 loads)
//       replacing reduce1+reduce2 (one fewer dispatch + gap)
//   (2) #pragma unroll 4 on the jj loop (was 2)

typedef float f32x2 __attribute__((ext_vector_type(2)));

#define NPTS   8192
#define BATCH  4
#define RPT    8                  // register-resident rows per thread
#define BLOCK  256
#define PTILE  (RPT * BLOCK)      // 2048 rows per block
#define NTILES (NPTS / PTILE)     // 4
#define CHUNK  128                // streamed cols per block
#define NPAIR  (CHUNK / 2)        // 64 column pairs
#define NCHUNK (NPTS / CHUNK)     // 64  -> grid 4*64*4 = 1024 blocks (4/CU)
#define NMINS  (2 * BATCH * NPTS) // 65536

__global__ __launch_bounds__(BLOCK, 4) void chamfer_pairs(
    const float* __restrict__ pred, const float* __restrict__ target,
    int* __restrict__ mins)
{
    __shared__ f32x2 qx2[NPAIR], qy2[NPAIR], qz2[NPAIR], qw2[NPAIR];
    __shared__ int   cmin_s[CHUNK];   // per-block column mins (int bits)

    const int b = blockIdx.z;
    const float* __restrict__ P = pred   + b * NPTS * 3;
    const float* __restrict__ Q = target + b * NPTS * 3;

    const int tid = threadIdx.x;
    const int i0  = blockIdx.x * PTILE + tid;
    const int j0  = blockIdx.y * CHUNK;

    if (tid < CHUNK) {
        const float* qp = Q + 3 * (j0 + tid);
        const float qx = qp[0], qy = qp[1], qz = qp[2];
        ((float*)qx2)[tid] = qx;
        ((float*)qy2)[tid] = qy;
        ((float*)qz2)[tid] = qz;
        ((float*)qw2)[tid] = fmaf(qx, qx, fmaf(qy, qy, qz * qz));
        cmin_s[tid] = 0x7F7F7F7F;   // 3.39e38f
    }
    __syncthreads();

    f32x2 pxn2[RPT], pyn2[RPT], pzn2[RPT], p22[RPT];
    float m[RPT];
#pragma unroll
    for (int r = 0; r < RPT; ++r) {
        const float* pp = P + 3 * (i0 + r * BLOCK);
        const float x = pp[0], y = pp[1], z = pp[2];
        const float nx = -2.0f * x, ny = -2.0f * y, nz = -2.0f * z;
        const float p2 = fmaf(x, x, fmaf(y, y, z * z));
        pxn2[r] = (f32x2){nx, nx};
        pyn2[r] = (f32x2){ny, ny};
        pzn2[r] = (f32x2){nz, nz};
        p22[r]  = (f32x2){p2, p2};
        m[r]    = 3.0e38f;
    }

    // per-lane staggered pair index, decorrelated across the 4 waves
    const int soff = (tid & 63) + ((tid >> 6) << 4);

#pragma unroll 4
    for (int jj = 0; jj < NPAIR; ++jj) {
        const int jp = (soff + jj) & (NPAIR - 1);
        const f32x2 qx = qx2[jp];      // ds_read_b64, packed {q[2jp],q[2jp+1]}
        const f32x2 qy = qy2[jp];
        const f32x2 qz = qz2[jp];
        const f32x2 qw = qw2[jp];

        f32x2 d[RPT];
#pragma unroll
        for (int r = 0; r < RPT; ++r) {
            f32x2 t = __builtin_elementwise_fma(pxn2[r], qx, qw);  // |q|^2 - 2p.q
            t = __builtin_elementwise_fma(pyn2[r], qy, t);
            t = __builtin_elementwise_fma(pzn2[r], qz, t);
            m[r] = fminf(fminf(m[r], t.x), t.y);   // v_min3, |p|^2 deferred
            d[r] = t + p22[r];                     // v_pk_add: full d^2 pair
        }
        // col-min trees per half, min3-friendly nesting
        const float cl = fminf(
            fminf(fminf(fminf(d[0].x, d[1].x), d[2].x),
                  fminf(fminf(d[3].x, d[4].x), d[5].x)),
            fminf(d[6].x, d[7].x));
        const float ch = fminf(
            fminf(fminf(fminf(d[0].y, d[1].y), d[2].y),
                  fminf(fminf(d[3].y, d[4].y), d[5].y)),
            fminf(d[6].y, d[7].y));
        atomicMin(&cmin_s[2 * jp],     __float_as_int(cl));
        atomicMin(&cmin_s[2 * jp + 1], __float_as_int(ch));
    }

    int* __restrict__ fwd = mins + b * NPTS;
    int* __restrict__ bwd = mins + (BATCH + b) * NPTS;
#pragma unroll
    for (int r = 0; r < RPT; ++r) {
        const float v = fmaxf(m[r] + p22[r].x, 0.0f);  // clamp commutes with min
        atomicMin(&fwd[i0 + r * BLOCK], __float_as_int(v));
    }
    __syncthreads();
    if (tid < CHUNK)
        atomicMin(&bwd[j0 + tid], cmin_s[tid]);
}

__global__ __launch_bounds__(1024) void chamfer_reduce(
    const int* __restrict__ mins, float* __restrict__ out)
{
    __shared__ float part[16];
    // 65536 ints / 1024 threads = 64 each = 16 int4 loads
    const int4* __restrict__ m4 = (const int4*)mins;   // 16384 int4s
    float s = 0.0f;
#pragma unroll 4
    for (int k = 0; k < 16; ++k) {
        const int4 v = m4[k * 1024 + threadIdx.x];
        s += fmaxf(__int_as_float(v.x), 0.0f) + fmaxf(__int_as_float(v.y), 0.0f) +
             fmaxf(__int_as_float(v.z), 0.0f) + fmaxf(__int_as_float(v.w), 0.0f);
    }

    for (int off = 32; off > 0; off >>= 1)
        s += __shfl_down(s, off, 64);
    if ((threadIdx.x & 63) == 0)
        part[threadIdx.x >> 6] = s;
    __syncthreads();

    if (threadIdx.x < 16) {
        float v = part[threadIdx.x];
        for (int off = 8; off > 0; off >>= 1)
            v += __shfl_down(v, off, 64);
        if (threadIdx.x == 0)
            out[0] = v * (1.0f / (float)(BATCH * NPTS));  // /32768
    }
}

extern "C" void kernel_launch(void* const* d_in, const int* in_sizes, int n_in,
                              void* d_out, int out_size, void* d_ws, size_t ws_size,
                              hipStream_t stream)
{
    const float* pred   = (const float*)d_in[0];
    const float* target = (const float*)d_in[1];
    float* out = (float*)d_out;
    int*   mins = (int*)d_ws;   // [2][BATCH][NPTS] fp32-as-int partial mins

    hipMemsetAsync(mins, 0x7F, (size_t)NMINS * sizeof(int), stream);

    dim3 grid(NTILES, NCHUNK, BATCH);
    chamfer_pairs<<<grid, BLOCK, 0, stream>>>(pred, target, mins);
    chamfer_reduce<<<1, 1024, 0, stream>>>(mins, out);
}

// Round 14
// 88.843 us; speedup vs baseline: 1.2661x; 1.0137x over previous
//
#include <hip/hip_runtime.h>

// Chamfer distance, pred/target: (4, 8192, 3) fp32.
// Round-13 structure with ONE change: hipMemsetAsync (suspected ~40 us
// fixed-cost fillBufferAligned) replaced by a tiny init kernel
// (64 blocks x 256 thr, int4 stores, ~2 us) that writes 0x7F7F7F7F
// into the 256 KB mins array.

typedef float f32x2 __attribute__((ext_vector_type(2)));

#define NPTS   8192
#define BATCH  4
#define RPT    8                  // register-resident rows per thread
#define BLOCK  256
#define PTILE  (RPT * BLOCK)      // 2048 rows per block
#define NTILES (NPTS / PTILE)     // 4
#define CHUNK  128                // streamed cols per block
#define NPAIR  (CHUNK / 2)        // 64 column pairs
#define NCHUNK (NPTS / CHUNK)     // 64  -> grid 4*64*4 = 1024 blocks (4/CU)
#define NMINS  (2 * BATCH * NPTS) // 65536

__global__ __launch_bounds__(256) void chamfer_init(int* __restrict__ mins)
{
    const int idx = blockIdx.x * 256 + threadIdx.x;       // 16384 int4 slots
    ((int4*)mins)[idx] = make_int4(0x7F7F7F7F, 0x7F7F7F7F,
                                   0x7F7F7F7F, 0x7F7F7F7F);
}

__global__ __launch_bounds__(BLOCK, 4) void chamfer_pairs(
    const float* __restrict__ pred, const float* __restrict__ target,
    int* __restrict__ mins)
{
    __shared__ f32x2 qx2[NPAIR], qy2[NPAIR], qz2[NPAIR], qw2[NPAIR];
    __shared__ int   cmin_s[CHUNK];   // per-block column mins (int bits)

    const int b = blockIdx.z;
    const float* __restrict__ P = pred   + b * NPTS * 3;
    const float* __restrict__ Q = target + b * NPTS * 3;

    const int tid = threadIdx.x;
    const int i0  = blockIdx.x * PTILE + tid;
    const int j0  = blockIdx.y * CHUNK;

    if (tid < CHUNK) {
        const float* qp = Q + 3 * (j0 + tid);
        const float qx = qp[0], qy = qp[1], qz = qp[2];
        ((float*)qx2)[tid] = qx;
        ((float*)qy2)[tid] = qy;
        ((float*)qz2)[tid] = qz;
        ((float*)qw2)[tid] = fmaf(qx, qx, fmaf(qy, qy, qz * qz));
        cmin_s[tid] = 0x7F7F7F7F;   // 3.39e38f
    }
    __syncthreads();

    f32x2 pxn2[RPT], pyn2[RPT], pzn2[RPT], p22[RPT];
    float m[RPT];
#pragma unroll
    for (int r = 0; r < RPT; ++r) {
        const float* pp = P + 3 * (i0 + r * BLOCK);
        const float x = pp[0], y = pp[1], z = pp[2];
        const float nx = -2.0f * x, ny = -2.0f * y, nz = -2.0f * z;
        const float p2 = fmaf(x, x, fmaf(y, y, z * z));
        pxn2[r] = (f32x2){nx, nx};
        pyn2[r] = (f32x2){ny, ny};
        pzn2[r] = (f32x2){nz, nz};
        p22[r]  = (f32x2){p2, p2};
        m[r]    = 3.0e38f;
    }

    // per-lane staggered pair index, decorrelated across the 4 waves
    const int soff = (tid & 63) + ((tid >> 6) << 4);

#pragma unroll 4
    for (int jj = 0; jj < NPAIR; ++jj) {
        const int jp = (soff + jj) & (NPAIR - 1);
        const f32x2 qx = qx2[jp];      // ds_read_b64, packed {q[2jp],q[2jp+1]}
        const f32x2 qy = qy2[jp];
        const f32x2 qz = qz2[jp];
        const f32x2 qw = qw2[jp];

        f32x2 d[RPT];
#pragma unroll
        for (int r = 0; r < RPT; ++r) {
            f32x2 t = __builtin_elementwise_fma(pxn2[r], qx, qw);  // |q|^2 - 2p.q
            t = __builtin_elementwise_fma(pyn2[r], qy, t);
            t = __builtin_elementwise_fma(pzn2[r], qz, t);
            m[r] = fminf(fminf(m[r], t.x), t.y);   // v_min3, |p|^2 deferred
            d[r] = t + p22[r];                     // v_pk_add: full d^2 pair
        }
        // col-min trees per half, min3-friendly nesting
        const float cl = fminf(
            fminf(fminf(fminf(d[0].x, d[1].x), d[2].x),
                  fminf(fminf(d[3].x, d[4].x), d[5].x)),
            fminf(d[6].x, d[7].x));
        const float ch = fminf(
            fminf(fminf(fminf(d[0].y, d[1].y), d[2].y),
                  fminf(fminf(d[3].y, d[4].y), d[5].y)),
            fminf(d[6].y, d[7].y));
        atomicMin(&cmin_s[2 * jp],     __float_as_int(cl));
        atomicMin(&cmin_s[2 * jp + 1], __float_as_int(ch));
    }

    int* __restrict__ fwd = mins + b * NPTS;
    int* __restrict__ bwd = mins + (BATCH + b) * NPTS;
#pragma unroll
    for (int r = 0; r < RPT; ++r) {
        const float v = fmaxf(m[r] + p22[r].x, 0.0f);  // clamp commutes with min
        atomicMin(&fwd[i0 + r * BLOCK], __float_as_int(v));
    }
    __syncthreads();
    if (tid < CHUNK)
        atomicMin(&bwd[j0 + tid], cmin_s[tid]);
}

__global__ __launch_bounds__(1024) void chamfer_reduce(
    const int* __restrict__ mins, float* __restrict__ out)
{
    __shared__ float part[16];
    // 65536 ints / 1024 threads = 64 each = 16 int4 loads
    const int4* __restrict__ m4 = (const int4*)mins;   // 16384 int4s
    float s = 0.0f;
#pragma unroll 4
    for (int k = 0; k < 16; ++k) {
        const int4 v = m4[k * 1024 + threadIdx.x];
        s += fmaxf(__int_as_float(v.x), 0.0f) + fmaxf(__int_as_float(v.y), 0.0f) +
             fmaxf(__int_as_float(v.z), 0.0f) + fmaxf(__int_as_float(v.w), 0.0f);
    }

    for (int off = 32; off > 0; off >>= 1)
        s += __shfl_down(s, off, 64);
    if ((threadIdx.x & 63) == 0)
        part[threadIdx.x >> 6] = s;
    __syncthreads();

    if (threadIdx.x < 16) {
        float v = part[threadIdx.x];
        for (int off = 8; off > 0; off >>= 1)
            v += __shfl_down(v, off, 64);
        if (threadIdx.x == 0)
            out[0] = v * (1.0f / (float)(BATCH * NPTS));  // /32768
    }
}

extern "C" void kernel_launch(void* const* d_in, const int* in_sizes, int n_in,
                              void* d_out, int out_size, void* d_ws, size_t ws_size,
                              hipStream_t stream)
{
    const float* pred   = (const float*)d_in[0];
    const float* target = (const float*)d_in[1];
    float* out = (float*)d_out;
    int*   mins = (int*)d_ws;   // [2][BATCH][NPTS] fp32-as-int partial mins

    chamfer_init<<<NMINS / 4 / 256, 256, 0, stream>>>(mins);

    dim3 grid(NTILES, NCHUNK, BATCH);
    chamfer_pairs<<<grid, BLOCK, 0, stream>>>(pred, target, mins);
    chamfer_reduce<<<1, 1024, 0, stream>>>(mins, out);
}